// Round 11
// baseline (4157.040 us; speedup 1.0000x reference)
//
#include <hip/hip_runtime.h>
#include <math.h>

#define N_NODES 50000
#define N_PAD   50048              // rows padded to multiple of 64
#define N_EDGES 1600000
#define DIM     128
#define RCUT    5.0f
#define NGROUP  (N_PAD / 64)       // 782 groups of 64 nodes
#define NB_PRE  512
#define CH_PRE  (N_EDGES / NB_PRE) // 3125 edges per preA histogram chunk
#define NB_CONV 6250               // convert blocks in preA
#define NB_WPREP 8                 // wprep blocks in preA
#define NB_SUB  8                  // b-subchunks for ktot2/kbase2
#define B_SUB   (NB_PRE / NB_SUB)  // 64
#define APAD    132                // accf row stride in floats (528 B, 16B-aligned)

typedef __attribute__((ext_vector_type(8))) __bf16 bf16x8;
typedef __attribute__((ext_vector_type(4))) float  f32x4;

// ---------------- bf16 helpers ----------------
__device__ __forceinline__ float bf_lo(unsigned int u) { return __uint_as_float(u << 16); }
__device__ __forceinline__ float bf_hi(unsigned int u) { return __uint_as_float(u & 0xffff0000u); }
__device__ __forceinline__ unsigned short f2bf(float x) {
    unsigned int u = __float_as_uint(x);
    u += 0x7fffu + ((u >> 16) & 1u);   // round-to-nearest-even
    return (unsigned short)(u >> 16);
}

// ---------------- preA: convert v->bf16  |  W->frags  |  group-64 histogram ---
__global__ __launch_bounds__(256) void preA_kernel(
        const float* __restrict__ v, unsigned short* __restrict__ vb,
        const float* __restrict__ Aw, uint4* __restrict__ wfrag,
        const int* __restrict__ dst, int* __restrict__ partial) {
    int b = blockIdx.x;
    if (b < NB_CONV) {
        int i = b * 256 + threadIdx.x;           // exactly N_NODES*DIM/4
        float4 x = ((const float4*)v)[i];
        uint2 o;
        o.x = (unsigned)f2bf(x.x) | ((unsigned)f2bf(x.y) << 16);
        o.y = (unsigned)f2bf(x.z) | ((unsigned)f2bf(x.w) << 16);
        ((uint2*)vb)[i] = o;
    } else if (b < NB_CONV + NB_WPREP) {
        int t = (b - NB_CONV) * 256 + threadIdx.x;   // 0..2047
        int lane = t & 63, nt = (t >> 6) & 7, kk = t >> 9;
        int n  = nt * 16 + (lane & 15);
        int k0 = kk * 32 + (lane >> 4) * 8;
        unsigned short h[8];
        #pragma unroll
        for (int i = 0; i < 8; ++i) h[i] = f2bf(Aw[n * DIM + k0 + i]);
        uint4 o;
        o.x = h[0] | ((unsigned)h[1] << 16); o.y = h[2] | ((unsigned)h[3] << 16);
        o.z = h[4] | ((unsigned)h[5] << 16); o.w = h[6] | ((unsigned)h[7] << 16);
        wfrag[t] = o;
    } else {
        __shared__ int h[NGROUP];                // 3.1 KB
        int cb = b - NB_CONV - NB_WPREP, tid = threadIdx.x;
        for (int g = tid; g < NGROUP; g += 256) h[g] = 0;
        __syncthreads();
        int beg = cb * CH_PRE, end = beg + CH_PRE;
        for (int i = beg + tid; i < end; i += 256)
            atomicAdd(&h[dst[i] >> 6], 1);       // LDS atomic
        __syncthreads();
        for (int g = tid; g < NGROUP; g += 256) partial[cb * NGROUP + g] = h[g];
    }
}

// ---------------- partial sums over b-subchunks (R4 verbatim) ----------------
__global__ __launch_bounds__(256) void ktot2_kernel(const int* __restrict__ partial,
                                                    int* __restrict__ partial2) {
    int gb = blockIdx.x & 3, bb = blockIdx.x >> 2;
    int g = gb * 256 + threadIdx.x;
    if (g >= NGROUP) return;
    int s = 0;
    int b0 = bb * B_SUB;
    for (int b = b0; b < b0 + B_SUB; ++b) s += partial[b * NGROUP + g];
    partial2[bb * NGROUP + g] = s;
}

// ---------------- exclusive scan over 782 group totals (R4 verbatim) --------
__global__ __launch_bounds__(256) void kscan_kernel(const int* __restrict__ partial2,
                                                    int* __restrict__ goff) {
    __shared__ int part[256];
    int tid = threadIdx.x;
    int i0 = tid * 4;
    int v[4]; int s = 0;
    #pragma unroll
    for (int k = 0; k < 4; ++k) {
        int i = i0 + k; int t = 0;
        if (i < NGROUP) {
            #pragma unroll
            for (int bb = 0; bb < NB_SUB; ++bb) t += partial2[bb * NGROUP + i];
        }
        v[k] = t; s += t;
    }
    part[tid] = s; __syncthreads();
    for (int d = 1; d < 256; d <<= 1) {
        int val = (tid >= d) ? part[tid - d] : 0;
        __syncthreads(); part[tid] += val; __syncthreads();
    }
    int run = (tid == 0) ? 0 : part[tid - 1];
    #pragma unroll
    for (int k = 0; k < 4; ++k) {
        int i = i0 + k;
        if (i < NGROUP) { goff[i] = run; run += v[k]; }
    }
    if (tid == 0) goff[NGROUP] = N_EDGES;
}

// ---------------- per-(block,group) bases (R4 verbatim) ----------------
__global__ __launch_bounds__(256) void kbase2_kernel(const int* __restrict__ partial,
                                                     const int* __restrict__ partial2,
                                                     const int* __restrict__ goff,
                                                     int* __restrict__ pbase) {
    int gb = blockIdx.x & 3, bb = blockIdx.x >> 2;
    int g = gb * 256 + threadIdx.x;
    if (g >= NGROUP) return;
    int run = goff[g];
    for (int b2 = 0; b2 < bb; ++b2) run += partial2[b2 * NGROUP + g];
    int b0 = bb * B_SUB;
    for (int b = b0; b < b0 + B_SUB; ++b) {
        pbase[b * NGROUP + g] = run;
        run += partial[b * NGROUP + g];
    }
}

// ---------------- reorder into group-64 CSR with 6-bit node tags (R4) ------
__global__ __launch_bounds__(512) void reorder_kernel(
        const float* __restrict__ e,
        const int*   __restrict__ src,
        const int*   __restrict__ dst,
        const float* __restrict__ rs,
        const float* __restrict__ sigma,
        const int*   __restrict__ pbase,
        int2* __restrict__ metaT) {
    __shared__ int base[NGROUP];
    __shared__ int cnt[NGROUP];
    int b = blockIdx.x, tid = threadIdx.x;
    for (int g = tid; g < NGROUP; g += 512) { base[g] = pbase[b * NGROUP + g]; cnt[g] = 0; }
    __syncthreads();
    float rsv = rs[0], sg = sigma[0];
    int beg = b * CH_PRE, end = beg + CH_PRE;
    for (int i = beg + tid; i < end; i += 512) {
        float r  = e[i];
        float d  = r - rsv;
        float gauss = expf(-(d * d) / (sg * sg));
        float cut   = 0.5f * cosf(r * (float)(M_PI / (double)RCUT));
        cut = (r < RCUT) ? cut : 0.0f;
        float fe = gauss * cut;
        int dn = dst[i];
        int g  = dn >> 6;
        int lr = atomicAdd(&cnt[g], 1);          // LDS atomic
        metaT[base[g] + lr] = make_int2(src[i] * (DIM * 2) | ((dn & 63) << 24),
                                        __float_as_int(fe));
    }
}

// ---------------- unified layer: stream unsorted group-CSR -> LDS f32 acc --
// One block per 64-node group. No tag sort, no per-node offsets: 8 waves
// stream contiguous 64-edge chunks; per edge, 64 lanes read the src row
// (coalesced 256B) and ds_add_f32 into accf[dst&63][*]. Then bias+ReLU GEMM.
__global__ __launch_bounds__(512) void layer_kernel(
        const unsigned short* __restrict__ cur,   // bf16 [N_PAD, DIM]
        const unsigned short* __restrict__ vb,    // bf16 skip (pristine v)
        const int2*  __restrict__ metaT,          // unsorted group-CSR, tagged
        const int*   __restrict__ goff,
        const uint4* __restrict__ wfrag,
        const float* __restrict__ bias,
        unsigned short* __restrict__ out_bf,
        float* __restrict__ out_f,
        int last) {
    __shared__ float accf[64][APAD];              // 33 KB (4 blocks/CU)
    int tid = threadIdx.x;
    int wv  = tid >> 6, lane = tid & 63;
    int g   = blockIdx.x;
    int n0  = g * 64;

    // ---- init accf with the skip (f32 of bf16 v), zeros for pad rows ----
    {
        int row = tid >> 3, c0 = (tid & 7) * 16;
        int n = n0 + row;
        if (n < N_NODES) {
            const unsigned* vp = (const unsigned*)(vb + (size_t)n * DIM + c0);
            #pragma unroll
            for (int k = 0; k < 8; ++k) {
                unsigned u = vp[k];
                accf[row][c0 + 2 * k]     = bf_lo(u);
                accf[row][c0 + 2 * k + 1] = bf_hi(u);
            }
        } else {
            #pragma unroll
            for (int k = 0; k < 16; ++k) accf[row][c0 + k] = 0.f;
        }
    }
    __syncthreads();

    // ---- edge streaming: 64-edge chunks round-robin over 8 waves ----
    int sbeg = goff[g], send = goff[g + 1];
    const char* basec = (const char*)cur + lane * 4;
    for (int base = sbeg + wv * 64; base < send; base += 512) {
        int cnt = send - base; if (cnt > 64) cnt = 64;
        int2 m = make_int2(0, 0);
        if (lane < cnt) m = metaT[base + lane];
        #pragma unroll 4
        for (int j = 0; j < cnt; ++j) {
            int mx = __builtin_amdgcn_readlane(m.x, j);
            int mf = __builtin_amdgcn_readlane(m.y, j);
            unsigned rr = *(const unsigned*)(basec + (mx & 0x00FFFFFF));
            float ff = __int_as_float(mf);
            int dl = (mx >> 24) & 63;
            atomicAdd(&accf[dl][lane * 2],     ff * bf_lo(rr));
            atomicAdd(&accf[dl][lane * 2 + 1], ff * bf_hi(rr));
        }
    }
    __syncthreads();

    // ---- GEMM: wave wv -> rows (wv>>1)*16..+15, col-half (wv&1) ----
    int quad = lane >> 4, l16 = lane & 15;
    int rb = wv >> 1, nh = wv & 1;
    f32x4 acc[4];
    #pragma unroll
    for (int j = 0; j < 4; ++j) acc[j] = (f32x4){0.f, 0.f, 0.f, 0.f};

    const float* xp = &accf[rb * 16 + l16][quad * 8];
    #pragma unroll
    for (int kk = 0; kk < 4; ++kk) {
        float4 xa = *(const float4*)(xp + kk * 32);
        float4 xb = *(const float4*)(xp + kk * 32 + 4);
        uint4 pk;
        pk.x = (unsigned)f2bf(xa.x) | ((unsigned)f2bf(xa.y) << 16);
        pk.y = (unsigned)f2bf(xa.z) | ((unsigned)f2bf(xa.w) << 16);
        pk.z = (unsigned)f2bf(xb.x) | ((unsigned)f2bf(xb.y) << 16);
        pk.w = (unsigned)f2bf(xb.z) | ((unsigned)f2bf(xb.w) << 16);
        bf16x8 af = __builtin_bit_cast(bf16x8, pk);
        #pragma unroll
        for (int j = 0; j < 4; ++j) {
            uint4 w = wfrag[(kk * 8 + nh * 4 + j) * 64 + lane];
            bf16x8 bfr = __builtin_bit_cast(bf16x8, w);
            acc[j] = __builtin_amdgcn_mfma_f32_16x16x32_bf16(af, bfr, acc[j], 0, 0, 0);
        }
    }

    int orow0 = g * 64 + rb * 16 + quad * 4;
    #pragma unroll
    for (int j = 0; j < 4; ++j) {
        int col = (nh * 4 + j) * 16 + l16;
        float b = bias[col];
        #pragma unroll
        for (int r = 0; r < 4; ++r) {
            int orow = orow0 + r;
            if (orow < N_NODES) {
                float val = fmaxf(acc[j][r] + b, 0.f);
                if (last) out_f[(size_t)orow * DIM + col] = val;
                else      out_bf[(size_t)orow * DIM + col] = f2bf(val);
            }
        }
    }
}

// ---------------------------------------------------------------------------
extern "C" void kernel_launch(void* const* d_in, const int* in_sizes, int n_in,
                              void* d_out, int out_size, void* d_ws, size_t ws_size,
                              hipStream_t stream) {
    const float* v     = (const float*)d_in[0];
    const float* e     = (const float*)d_in[1];
    const int*   src   = (const int*)  d_in[2];
    const int*   dst   = (const int*)  d_in[3];
    const float* Aw    = (const float*)d_in[4];
    const float* Ab    = (const float*)d_in[5];
    const float* rs    = (const float*)d_in[6];
    const float* sigma = (const float*)d_in[7];
    float* out = (float*)d_out;

    // ---- workspace layout (~51.5 MB) ----
    char* p = (char*)d_ws;
    int2*           metaT = (int2*)p;            p += (size_t)N_EDGES * 8;       // 12.8 MB (group-CSR, live all layers)
    unsigned short* bufV  = (unsigned short*)p;  p += (size_t)N_PAD * DIM * 2;   // 12.81 MB (pristine bf16 v)
    unsigned short* bufA  = (unsigned short*)p;  p += (size_t)N_PAD * DIM * 2;   // 12.81 MB (L1 out)
    unsigned short* bufB  = (unsigned short*)p;  p += (size_t)N_PAD * DIM * 2;   // 12.81 MB (partials / L0 out)
    uint4*          wfrag = (uint4*)p;           p += 2048 * 16;                 //  32 KB
    int*            goff  = (int*)p;             p += (NGROUP + 2) * 4;
    // aliases inside bufB (dead before L0's first write):
    int*  partial  = (int*)bufB;                 // [512][NGROUP] = 1.6 MB
    int*  pbase    = partial + NB_PRE * NGROUP;  // 1.6 MB, dead after reorder
    int*  partial2 = pbase + NB_PRE * NGROUP;    // [8][NGROUP] = 25 KB

    preA_kernel<<<NB_CONV + NB_WPREP + NB_PRE, 256, 0, stream>>>(
        v, bufV, Aw, wfrag, dst, partial);
    ktot2_kernel<<<4 * NB_SUB, 256, 0, stream>>>(partial, partial2);
    kscan_kernel<<<1, 256, 0, stream>>>(partial2, goff);
    kbase2_kernel<<<4 * NB_SUB, 256, 0, stream>>>(partial, partial2, goff, pbase);
    reorder_kernel<<<NB_PRE, 512, 0, stream>>>(e, src, dst, rs, sigma, pbase, metaT);

    // three unified layers, all consuming the unsorted group-CSR directly
    layer_kernel<<<NGROUP, 512, 0, stream>>>(
        bufV, bufV, metaT, goff, wfrag, Ab, bufB, nullptr, 0);
    layer_kernel<<<NGROUP, 512, 0, stream>>>(
        bufB, bufV, metaT, goff, wfrag, Ab, bufA, nullptr, 0);
    layer_kernel<<<NGROUP, 512, 0, stream>>>(
        bufA, bufV, metaT, goff, wfrag, Ab, nullptr, out, 1);
}

// Round 12
// 318.276 us; speedup vs baseline: 13.0611x; 13.0611x over previous
//
#include <hip/hip_runtime.h>
#include <math.h>

#define N_NODES 50000
#define N_PAD   50048              // rows padded to multiple of 64
#define N_EDGES 1600000
#define DIM     128
#define RCUT    5.0f
#define NGROUP  (N_PAD / 64)       // 782 groups of 64 nodes
#define NB_PRE  512
#define CH_PRE  (N_EDGES / NB_PRE) // 3125 edges per preA histogram chunk
#define NB_CONV 6250               // convert blocks in preA
#define NB_WPREP 8                 // wprep blocks in preA
#define NB_SUB  8                  // b-subchunks (kmid phase 1/3)
#define B_SUB   (NB_PRE / NB_SUB)  // 64
#define XPAD    136                // LDS X tile row stride in bf16 (272 B)
#define NTILE   (N_PAD / 16)       // 3128 16-node tiles for layer12
#define NB_MID  32                 // kmid grid (co-resident by construction)

typedef __attribute__((ext_vector_type(8))) __bf16 bf16x8;
typedef __attribute__((ext_vector_type(4))) float  f32x4;

// ---------------- bf16 helpers ----------------
__device__ __forceinline__ float bf_lo(unsigned int u) { return __uint_as_float(u << 16); }
__device__ __forceinline__ float bf_hi(unsigned int u) { return __uint_as_float(u & 0xffff0000u); }
__device__ __forceinline__ unsigned short f2bf(float x) {
    unsigned int u = __float_as_uint(x);
    u += 0x7fffu + ((u >> 16) & 1u);   // round-to-nearest-even
    return (unsigned short)(u >> 16);
}

// ---------------- preA: convert v->bf16 | W->frags | group-64 histogram ----
// Block NB_CONV additionally zeroes the kmid barrier words (stream-ordered
// before kmid's launch, so visibility is guaranteed by the kernel boundary).
__global__ __launch_bounds__(256) void preA_kernel(
        const float* __restrict__ v, unsigned short* __restrict__ vb,
        const float* __restrict__ Aw, uint4* __restrict__ wfrag,
        const int* __restrict__ dst, int* __restrict__ partial,
        int* __restrict__ bar) {
    int b = blockIdx.x;
    if (b < NB_CONV) {
        int i = b * 256 + threadIdx.x;           // exactly N_NODES*DIM/4
        float4 x = ((const float4*)v)[i];
        uint2 o;
        o.x = (unsigned)f2bf(x.x) | ((unsigned)f2bf(x.y) << 16);
        o.y = (unsigned)f2bf(x.z) | ((unsigned)f2bf(x.w) << 16);
        ((uint2*)vb)[i] = o;
    } else if (b < NB_CONV + NB_WPREP) {
        int t = (b - NB_CONV) * 256 + threadIdx.x;   // 0..2047
        if (b == NB_CONV && threadIdx.x <= NB_MID)   // zero 32 arrival lines + rel
            bar[threadIdx.x * 32] = 0;
        int lane = t & 63, nt = (t >> 6) & 7, kk = t >> 9;
        int n  = nt * 16 + (lane & 15);
        int k0 = kk * 32 + (lane >> 4) * 8;
        unsigned short h[8];
        #pragma unroll
        for (int i = 0; i < 8; ++i) h[i] = f2bf(Aw[n * DIM + k0 + i]);
        uint4 o;
        o.x = h[0] | ((unsigned)h[1] << 16); o.y = h[2] | ((unsigned)h[3] << 16);
        o.z = h[4] | ((unsigned)h[5] << 16); o.w = h[6] | ((unsigned)h[7] << 16);
        wfrag[t] = o;
    } else {
        __shared__ int h[NGROUP];                // 3.1 KB
        int cb = b - NB_CONV - NB_WPREP, tid = threadIdx.x;
        for (int g = tid; g < NGROUP; g += 256) h[g] = 0;
        __syncthreads();
        int beg = cb * CH_PRE, end = beg + CH_PRE;
        for (int i = beg + tid; i < end; i += 256)
            atomicAdd(&h[dst[i] >> 6], 1);       // LDS atomic
        __syncthreads();
        for (int g = tid; g < NGROUP; g += 256) partial[cb * NGROUP + g] = h[g];
    }
}

// ---------------- kmid: ktot2 + (replicated) kscan + kbase2, one barrier ---
// 32 blocks x 256 threads, all co-resident. One low-contention grid sync:
// one arrival line per block; block 0 aggregates; release on separate line.
__device__ __forceinline__ void gsync32(int* bar) {
    int* rel = bar + NB_MID * 32;
    __syncthreads();
    if (threadIdx.x == 0) {
        __threadfence();                          // release: publish phase-1 stores
        __hip_atomic_store(&bar[blockIdx.x * 32], 1,
                           __ATOMIC_RELAXED, __HIP_MEMORY_SCOPE_AGENT);
    }
    if (blockIdx.x == 0) {
        if (threadIdx.x < NB_MID) {
            int* cp = &bar[threadIdx.x * 32];
            while (__hip_atomic_load(cp, __ATOMIC_RELAXED,
                                     __HIP_MEMORY_SCOPE_AGENT) == 0)
                __builtin_amdgcn_s_sleep(1);
        }
        __syncthreads();                          // all 32 observed
        if (threadIdx.x == 0) {
            __threadfence();
            __hip_atomic_store(rel, 1, __ATOMIC_RELAXED, __HIP_MEMORY_SCOPE_AGENT);
        }
    }
    if (threadIdx.x == 0) {
        while (__hip_atomic_load(rel, __ATOMIC_RELAXED,
                                 __HIP_MEMORY_SCOPE_AGENT) == 0)
            __builtin_amdgcn_s_sleep(1);
        __threadfence();                          // acquire
    }
    __syncthreads();
}

__global__ __launch_bounds__(256) void kmid_kernel(
        const int* __restrict__ partial,
        int* __restrict__ partial2,
        int* __restrict__ goff,
        int* __restrict__ pbase,
        int* __restrict__ bar) {
    __shared__ int part[256];
    __shared__ int goffL[NGROUP];                 // 3.1 KB
    int tid = threadIdx.x, bid = blockIdx.x;
    int gb = bid & 3, bb = bid >> 2;
    int g = gb * 256 + tid;

    // ---- phase 1: partial2[bb][g] (= R4 ktot2) ----
    if (g < NGROUP) {
        int s = 0;
        int b0 = bb * B_SUB;
        for (int b = b0; b < b0 + B_SUB; ++b) s += partial[b * NGROUP + g];
        partial2[bb * NGROUP + g] = s;
    }
    gsync32(bar);

    // ---- phase 2: replicated scan over group totals (= R4 kscan) ----
    int i0 = tid * 4;
    int v[4]; int s = 0;
    #pragma unroll
    for (int k = 0; k < 4; ++k) {
        int i = i0 + k; int t = 0;
        if (i < NGROUP) {
            #pragma unroll
            for (int b2 = 0; b2 < NB_SUB; ++b2) t += partial2[b2 * NGROUP + i];
        }
        v[k] = t; s += t;
    }
    part[tid] = s; __syncthreads();
    for (int d = 1; d < 256; d <<= 1) {
        int val = (tid >= d) ? part[tid - d] : 0;
        __syncthreads(); part[tid] += val; __syncthreads();
    }
    int run = (tid == 0) ? 0 : part[tid - 1];
    #pragma unroll
    for (int k = 0; k < 4; ++k) {
        int i = i0 + k;
        if (i < NGROUP) {
            goffL[i] = run;
            if (bid == 0) goff[i] = run;
            run += v[k];
        }
    }
    if (bid == 0 && tid == 0) goff[NGROUP] = N_EDGES;
    __syncthreads();

    // ---- phase 3: per-(block,group) bases (= R4 kbase2) ----
    if (g < NGROUP) {
        int r = goffL[g];
        for (int b2 = 0; b2 < bb; ++b2) r += partial2[b2 * NGROUP + g];
        int b0 = bb * B_SUB;
        for (int b = b0; b < b0 + B_SUB; ++b) {
            pbase[b * NGROUP + g] = r;
            r += partial[b * NGROUP + g];
        }
    }
}

// ---------------- reorder into group-64 CSR with 6-bit node tags (R4) ------
__global__ __launch_bounds__(512) void reorder_kernel(
        const float* __restrict__ e,
        const int*   __restrict__ src,
        const int*   __restrict__ dst,
        const float* __restrict__ rs,
        const float* __restrict__ sigma,
        const int*   __restrict__ pbase,
        int2* __restrict__ metaT) {
    __shared__ int base[NGROUP];
    __shared__ int cnt[NGROUP];
    int b = blockIdx.x, tid = threadIdx.x;
    for (int g = tid; g < NGROUP; g += 512) { base[g] = pbase[b * NGROUP + g]; cnt[g] = 0; }
    __syncthreads();
    float rsv = rs[0], sg = sigma[0];
    int beg = b * CH_PRE, end = beg + CH_PRE;
    for (int i = beg + tid; i < end; i += 512) {
        float r  = e[i];
        float d  = r - rsv;
        float gauss = expf(-(d * d) / (sg * sg));
        float cut   = 0.5f * cosf(r * (float)(M_PI / (double)RCUT));
        cut = (r < RCUT) ? cut : 0.0f;
        float fe = gauss * cut;
        int dn = dst[i];
        int g  = dn >> 6;
        int lr = atomicAdd(&cnt[g], 1);          // LDS atomic
        metaT[base[g] + lr] = make_int2(src[i] * (DIM * 2) | ((dn & 63) << 24),
                                        __float_as_int(fe));
    }
}

// ---------------- shared gather inner loop (int2 meta, R4-proven) ----------
#define EDGE2(mx, mf, rr)                                        \
    do {                                                         \
        float ff = __int_as_float(mf);                           \
        a0 = fmaf(ff, bf_lo(rr), a0);                            \
        a1 = fmaf(ff, bf_hi(rr), a1);                            \
    } while (0)

__device__ __forceinline__ void gather_node(
        const int2* __restrict__ meta, const char* basec,
        int beg, int end, float& a0, float& a1) {
    int c = beg;
    if ((c & 1) && c < end) {
        int2 m = meta[c];
        unsigned rr = *(const unsigned*)(basec + (unsigned)m.x);
        EDGE2(m.x, m.y, rr);
        ++c;
    }
    for (; c + 16 <= end; c += 16) {
        int4 m0 = *(const int4*)(meta + c);
        int4 m1 = *(const int4*)(meta + c + 2);
        int4 m2 = *(const int4*)(meta + c + 4);
        int4 m3 = *(const int4*)(meta + c + 6);
        int4 m4 = *(const int4*)(meta + c + 8);
        int4 m5 = *(const int4*)(meta + c + 10);
        int4 m6 = *(const int4*)(meta + c + 12);
        int4 m7 = *(const int4*)(meta + c + 14);
        unsigned r0  = *(const unsigned*)(basec + (unsigned)m0.x);
        unsigned r1  = *(const unsigned*)(basec + (unsigned)m0.z);
        unsigned r2  = *(const unsigned*)(basec + (unsigned)m1.x);
        unsigned r3  = *(const unsigned*)(basec + (unsigned)m1.z);
        unsigned r4  = *(const unsigned*)(basec + (unsigned)m2.x);
        unsigned r5  = *(const unsigned*)(basec + (unsigned)m2.z);
        unsigned r6  = *(const unsigned*)(basec + (unsigned)m3.x);
        unsigned r7  = *(const unsigned*)(basec + (unsigned)m3.z);
        unsigned r8  = *(const unsigned*)(basec + (unsigned)m4.x);
        unsigned r9  = *(const unsigned*)(basec + (unsigned)m4.z);
        unsigned r10 = *(const unsigned*)(basec + (unsigned)m5.x);
        unsigned r11 = *(const unsigned*)(basec + (unsigned)m5.z);
        unsigned r12 = *(const unsigned*)(basec + (unsigned)m6.x);
        unsigned r13 = *(const unsigned*)(basec + (unsigned)m6.z);
        unsigned r14 = *(const unsigned*)(basec + (unsigned)m7.x);
        unsigned r15 = *(const unsigned*)(basec + (unsigned)m7.z);
        EDGE2(m0.x, m0.y, r0);  EDGE2(m0.z, m0.w, r1);
        EDGE2(m1.x, m1.y, r2);  EDGE2(m1.z, m1.w, r3);
        EDGE2(m2.x, m2.y, r4);  EDGE2(m2.z, m2.w, r5);
        EDGE2(m3.x, m3.y, r6);  EDGE2(m3.z, m3.w, r7);
        EDGE2(m4.x, m4.y, r8);  EDGE2(m4.z, m4.w, r9);
        EDGE2(m5.x, m5.y, r10); EDGE2(m5.z, m5.w, r11);
        EDGE2(m6.x, m6.y, r12); EDGE2(m6.z, m6.w, r13);
        EDGE2(m7.x, m7.y, r14); EDGE2(m7.z, m7.w, r15);
    }
    if (c + 8 <= end) {
        int4 m0 = *(const int4*)(meta + c);
        int4 m1 = *(const int4*)(meta + c + 2);
        int4 m2 = *(const int4*)(meta + c + 4);
        int4 m3 = *(const int4*)(meta + c + 6);
        unsigned r0 = *(const unsigned*)(basec + (unsigned)m0.x);
        unsigned r1 = *(const unsigned*)(basec + (unsigned)m0.z);
        unsigned r2 = *(const unsigned*)(basec + (unsigned)m1.x);
        unsigned r3 = *(const unsigned*)(basec + (unsigned)m1.z);
        unsigned r4 = *(const unsigned*)(basec + (unsigned)m2.x);
        unsigned r5 = *(const unsigned*)(basec + (unsigned)m2.z);
        unsigned r6 = *(const unsigned*)(basec + (unsigned)m3.x);
        unsigned r7 = *(const unsigned*)(basec + (unsigned)m3.z);
        EDGE2(m0.x, m0.y, r0); EDGE2(m0.z, m0.w, r1);
        EDGE2(m1.x, m1.y, r2); EDGE2(m1.z, m1.w, r3);
        EDGE2(m2.x, m2.y, r4); EDGE2(m2.z, m2.w, r5);
        EDGE2(m3.x, m3.y, r6); EDGE2(m3.z, m3.w, r7);
        c += 8;
    }
    for (; c < end; ++c) {
        int2 m = meta[c];
        unsigned rr = *(const unsigned*)(basec + (unsigned)m.x);
        EDGE2(m.x, m.y, rr);
    }
}

// ---------------- layer 0: tagsort + gather + GEMM (R4 verbatim) -----------
__global__ __launch_bounds__(512) void layer0_kernel(
        const unsigned short* __restrict__ cur,   // bf16 (= vb for L0)
        const unsigned short* __restrict__ vb,
        const int2*  __restrict__ metaT,          // group-CSR, tagged
        const int*   __restrict__ goff,
        int2* __restrict__ meta,                  // out: node-exact CSR
        int*  __restrict__ off,                   // out: node offsets
        const uint4* __restrict__ wfrag,
        const float* __restrict__ bias,
        unsigned short* __restrict__ out_bf) {
    __shared__ unsigned short xlds[64 * XPAD];    // 17408 B
    __shared__ int c64[64], b64[65], cu64[64];
    int tid = threadIdx.x;
    int wv  = tid >> 6, lane = tid & 63;
    int g   = blockIdx.x;
    int sbeg = goff[g], send = goff[g + 1];

    // ---- tagsort: 64-bin count + scan + scatter into node-exact meta ----
    if (tid < 64) c64[tid] = 0;
    __syncthreads();
    for (int i = sbeg + tid; i < send; i += 512)
        atomicAdd(&c64[(metaT[i].x >> 24) & 63], 1);
    __syncthreads();
    if (tid == 0) {
        int run = 0;
        #pragma unroll
        for (int t = 0; t < 64; ++t) { b64[t] = run; cu64[t] = run; run += c64[t]; }
        b64[64] = run;
    }
    __syncthreads();
    if (tid < 64) {
        int node = g * 64 + tid;
        if (node <= N_NODES) off[node] = sbeg + b64[tid];
    }
    for (int i = sbeg + tid; i < send; i += 512) {
        int2 m = metaT[i];
        int tag = (m.x >> 24) & 63;
        int lr = atomicAdd(&cu64[tag], 1);
        meta[sbeg + lr] = make_int2(m.x & 0x00FFFFFF, m.y);
    }
    __syncthreads();   // meta writes drained; b64 stable

    // ---- gather (offsets from LDS b64) ----
    int n0 = g * 64 + wv * 8;
    int myoff = 0;
    if (lane < 9) myoff = sbeg + b64[wv * 8 + lane];
    const char* basec = (const char*)cur + lane * 4;

    #pragma unroll 1
    for (int q = 0; q < 8; ++q) {
        int nl = wv * 8 + q;
        int n  = n0 + q;
        float a0 = 0.f, a1 = 0.f;
        if (n < N_NODES) {
            unsigned vv = *(const unsigned*)((const char*)vb + (size_t)n * (DIM * 2) + lane * 4);
            a0 = bf_lo(vv); a1 = bf_hi(vv);
            int beg = __builtin_amdgcn_readlane(myoff, q);
            int end = __builtin_amdgcn_readlane(myoff, q + 1);
            gather_node(meta, basec, beg, end, a0, a1);
        }
        *(unsigned*)(xlds + nl * XPAD + lane * 2) =
            (unsigned)f2bf(a0) | ((unsigned)f2bf(a1) << 16);
    }
    __syncthreads();

    // ---- GEMM: wave wv -> rows (wv>>1)*16..+15, col-half (wv&1) ----
    int quad = lane >> 4, l16 = lane & 15;
    int rb = wv >> 1, nh = wv & 1;
    f32x4 acc[4];
    #pragma unroll
    for (int j = 0; j < 4; ++j) acc[j] = (f32x4){0.f, 0.f, 0.f, 0.f};

    const unsigned short* xp = xlds + (rb * 16 + l16) * XPAD + quad * 8;
    #pragma unroll
    for (int kk = 0; kk < 4; ++kk) {
        bf16x8 af = *(const bf16x8*)(xp + kk * 32);
        #pragma unroll
        for (int j = 0; j < 4; ++j) {
            uint4 w = wfrag[(kk * 8 + nh * 4 + j) * 64 + lane];
            bf16x8 bfr = __builtin_bit_cast(bf16x8, w);
            acc[j] = __builtin_amdgcn_mfma_f32_16x16x32_bf16(af, bfr, acc[j], 0, 0, 0);
        }
    }

    int orow0 = g * 64 + rb * 16 + quad * 4;
    #pragma unroll
    for (int j = 0; j < 4; ++j) {
        int col = (nh * 4 + j) * 16 + l16;
        float b = bias[col];
        #pragma unroll
        for (int r = 0; r < 4; ++r) {
            int orow = orow0 + r;
            if (orow < N_NODES)
                out_bf[(size_t)orow * DIM + col] = f2bf(fmaxf(acc[j][r] + b, 0.f));
        }
    }
}

// ---------------- layers 1/2: 2-wave 16-node fused gather+GEMM (R4) --------
__global__ __launch_bounds__(128, 8) void layer12_kernel(
        const unsigned short* __restrict__ cur,
        const unsigned short* __restrict__ vb,
        const int2*  __restrict__ meta,
        const int*   __restrict__ off,
        const uint4* __restrict__ wfrag,
        const float* __restrict__ bias,
        unsigned short* __restrict__ out_bf,
        float* __restrict__ out_f,
        int last) {
    __shared__ unsigned short xlds[16 * XPAD];    // 4352 B
    int tid = threadIdx.x;
    int wv  = tid >> 6, lane = tid & 63;          // wv in {0,1}
    int tile = blockIdx.x;
    int n0  = tile * 16 + wv * 8;

    int offidx = n0 + ((lane < 9) ? lane : 8);
    if (offidx > N_NODES) offidx = N_NODES;
    int myoff = off[offidx];
    const char* basec = (const char*)cur + lane * 4;

    #pragma unroll 1
    for (int q = 0; q < 8; ++q) {
        int nl = wv * 8 + q;
        int n  = n0 + q;
        float a0 = 0.f, a1 = 0.f;
        if (n < N_NODES) {
            unsigned vv = *(const unsigned*)((const char*)vb + (size_t)n * (DIM * 2) + lane * 4);
            a0 = bf_lo(vv); a1 = bf_hi(vv);
            int beg = __builtin_amdgcn_readlane(myoff, q);
            int end = __builtin_amdgcn_readlane(myoff, q + 1);
            gather_node(meta, basec, beg, end, a0, a1);
        }
        *(unsigned*)(xlds + nl * XPAD + lane * 2) =
            (unsigned)f2bf(a0) | ((unsigned)f2bf(a1) << 16);
    }
    __syncthreads();

    // ---- GEMM: both waves cover all 16 rows; wave = col-half ----
    int quad = lane >> 4, l16 = lane & 15;
    f32x4 acc[4];
    #pragma unroll
    for (int j = 0; j < 4; ++j) acc[j] = (f32x4){0.f, 0.f, 0.f, 0.f};

    const unsigned short* xp = xlds + l16 * XPAD + quad * 8;
    #pragma unroll
    for (int kk = 0; kk < 4; ++kk) {
        bf16x8 af = *(const bf16x8*)(xp + kk * 32);
        #pragma unroll
        for (int j = 0; j < 4; ++j) {
            uint4 w = wfrag[(kk * 8 + wv * 4 + j) * 64 + lane];
            bf16x8 bfr = __builtin_bit_cast(bf16x8, w);
            acc[j] = __builtin_amdgcn_mfma_f32_16x16x32_bf16(af, bfr, acc[j], 0, 0, 0);
        }
    }

    int orow0 = tile * 16 + quad * 4;
    #pragma unroll
    for (int j = 0; j < 4; ++j) {
        int col = (wv * 4 + j) * 16 + l16;
        float b = bias[col];
        #pragma unroll
        for (int r = 0; r < 4; ++r) {
            int orow = orow0 + r;
            if (orow < N_NODES) {
                float val = fmaxf(acc[j][r] + b, 0.f);
                if (last) out_f[(size_t)orow * DIM + col] = val;
                else      out_bf[(size_t)orow * DIM + col] = f2bf(val);
            }
        }
    }
}

// ---------------------------------------------------------------------------
extern "C" void kernel_launch(void* const* d_in, const int* in_sizes, int n_in,
                              void* d_out, int out_size, void* d_ws, size_t ws_size,
                              hipStream_t stream) {
    const float* v     = (const float*)d_in[0];
    const float* e     = (const float*)d_in[1];
    const int*   src   = (const int*)  d_in[2];
    const int*   dst   = (const int*)  d_in[3];
    const float* Aw    = (const float*)d_in[4];
    const float* Ab    = (const float*)d_in[5];
    const float* rs    = (const float*)d_in[6];
    const float* sigma = (const float*)d_in[7];
    float* out = (float*)d_out;

    // ---- workspace layout (~51.5 MB) ----
    char* p = (char*)d_ws;
    int2*           meta  = (int2*)p;            p += (size_t)N_EDGES * 8;       // 12.8 MB (final CSR)
    unsigned short* bufV  = (unsigned short*)p;  p += (size_t)N_PAD * DIM * 2;   // 12.81 MB (pristine bf16 v)
    unsigned short* bufA  = (unsigned short*)p;  p += (size_t)N_PAD * DIM * 2;   // 12.81 MB (metaT / L1 out)
    unsigned short* bufB  = (unsigned short*)p;  p += (size_t)N_PAD * DIM * 2;   // 12.81 MB (partials / L0 out)
    uint4*          wfrag = (uint4*)p;           p += 2048 * 16;                 //  32 KB
    int*            off   = (int*)p;             p += (size_t)(N_NODES + 2) * 4;
    int*            goff  = (int*)p;             p += (NGROUP + 2) * 4;
    int*            bar   = (int*)p;             p += (NB_MID + 1) * 32 * 4;     // 4.2 KB barrier lines
    // aliases (dead before host buffer's first real write):
    int2* metaT    = (int2*)bufA;                // unsorted group-CSR, dead after layer0
    int*  partial  = (int*)bufB;                 // [512][NGROUP] = 1.6 MB
    int*  pbase    = partial + NB_PRE * NGROUP;  // 1.6 MB, dead after reorder
    int*  partial2 = pbase + NB_PRE * NGROUP;    // [8][NGROUP] = 25 KB

    // preA also zeroes the kmid barrier words (stream-ordered before kmid)
    preA_kernel<<<NB_CONV + NB_WPREP + NB_PRE, 256, 0, stream>>>(
        v, bufV, Aw, wfrag, dst, partial, bar);
    // merged ktot2 + kscan + kbase2 (one 32-block kernel, one grid sync)
    kmid_kernel<<<NB_MID, 256, 0, stream>>>(partial, partial2, goff, pbase, bar);
    reorder_kernel<<<NB_PRE, 512, 0, stream>>>(e, src, dst, rs, sigma, pbase, metaT);

    // L0: tagsort + gather(bufV) + gemm -> bufB   (consumes metaT in bufA)
    layer0_kernel<<<NGROUP, 512, 0, stream>>>(
        bufV, bufV, metaT, goff, meta, off, wfrag, Ab, bufB);
    // L1: gather(bufB) + gemm -> bufA
    layer12_kernel<<<NTILE, 128, 0, stream>>>(
        bufB, bufV, meta, off, wfrag, Ab, bufA, nullptr, 0);
    // L2: gather(bufA) + gemm -> out (fp32)
    layer12_kernel<<<NTILE, 128, 0, stream>>>(
        bufA, bufV, meta, off, wfrag, Ab, nullptr, out, 1);
}